// Round 6
// baseline (385.177 us; speedup 1.0000x reference)
//
#include <hip/hip_runtime.h>
#include <hip/hip_bf16.h>
#include <math.h>

// B=2 S=2048 D=1024 H=16 DH=64 F=4096. ALL inputs/outputs fp32.
// Internals bf16 (MFMA) with fp32 accumulate; residual stream fp32 in d_out.
// Workspace (64 MiB):
//   [0,6)   Wqkv_b  [6,8) Wout_b  [8,16) W1_b  [16,24) W2_b  (contiguous: cvt4)
//   [24,32) h (LN outputs)
//   [32,48) qk [4096][2048] bf16   [48,56) vt [32][64][2048] bf16 V^T
//   [56,64) attn [4096][1024] bf16
//   [32,64) act [4096][4096] bf16 (FFN, aliases qk/vt/attn after attention)
//   x2 fp32 = d_out (out-proj writes; LN2 reads; FFN2 atomicAdds in place)
//
// GEMM engines (round 6):
//   QKV, FFN1, FFN2 -> gemm256_8ph: 256x256/BK=64 8-phase counted-vmcnt
//     (r3-verified structure; swizzle FIXED to ((row>>1)&3) both sides —
//      r3's (row&3) was a 4-way bank conflict, 3.1M/dispatch)
//   out-proj -> gemm_bt 2-buf 128^2 (r0-verified)

typedef __bf16 bf16;
typedef __bf16 bf16x4 __attribute__((ext_vector_type(4)));
typedef __bf16 bf16x8 __attribute__((ext_vector_type(8)));
typedef float f32x4 __attribute__((ext_vector_type(4)));

#define LOG2E 1.4426950408889634f
#define NSHIFT -17.312340489f   // -12 * log2(e): fixed softmax shift of 12

__device__ __forceinline__ f32x4 mfma16(bf16x8 a, bf16x8 b, f32x4 c) {
    return __builtin_amdgcn_mfma_f32_16x16x32_bf16(a, b, c, 0, 0, 0);
}
// async global->LDS, 16B per lane; LDS dest = wave-uniform base + lane*16
__device__ __forceinline__ void load16_lds(const bf16* g, bf16* l) {
    __builtin_amdgcn_global_load_lds(
        (__attribute__((address_space(1))) void*)g,
        (__attribute__((address_space(3))) void*)l, 16, 0, 0);
}

// ---------------------------------------------------------------------------
// All four weight tensors fp32 -> bf16 in one launch; dst regions contiguous.
// ---------------------------------------------------------------------------
__global__ __launch_bounds__(256) void cvt4_kernel(const float* __restrict__ s0,
                                                   const float* __restrict__ s1,
                                                   const float* __restrict__ s2,
                                                   const float* __restrict__ s3,
                                                   bf16* __restrict__ dst) {
    const int blk = blockIdx.x;
    const float* s;
    int base;
    if (blk < 3072)      { s = s0; base = blk * 1024; }
    else if (blk < 4096) { s = s1; base = (blk - 3072) * 1024; }
    else if (blk < 8192) { s = s2; base = (blk - 4096) * 1024; }
    else                 { s = s3; base = (blk - 8192) * 1024; }
    const int t4 = threadIdx.x * 4;
    const float4 f = *(const float4*)(s + base + t4);
    bf16x4 o;
    o[0] = (bf16)f.x; o[1] = (bf16)f.y; o[2] = (bf16)f.z; o[3] = (bf16)f.w;
    *(bf16x4*)(dst + (size_t)blk * 1024 + t4) = o;
}

// ---------------------------------------------------------------------------
// LayerNorm row of 1024: fp32 in -> bf16 out. (x-mean)/(sqrt(var)+eps)
// ---------------------------------------------------------------------------
__global__ __launch_bounds__(256) void ln_kernel(const float* __restrict__ xin,
                                                 bf16* __restrict__ out,
                                                 const float* __restrict__ gamma,
                                                 const float* __restrict__ beta) {
    const int row = blockIdx.x;
    const int tid = threadIdx.x;
    const float4 f = *(const float4*)(xin + (size_t)row * 1024 + tid * 4);
    float v[4] = {f.x, f.y, f.z, f.w};
    float s = v[0] + v[1] + v[2] + v[3];
    float s2 = v[0] * v[0] + v[1] * v[1] + v[2] * v[2] + v[3] * v[3];
#pragma unroll
    for (int off = 1; off < 64; off <<= 1) {
        s += __shfl_xor(s, off);
        s2 += __shfl_xor(s2, off);
    }
    __shared__ float red[8];
    const int wave = tid >> 6, lane = tid & 63;
    if (lane == 0) { red[wave] = s; red[4 + wave] = s2; }
    __syncthreads();
    s = red[0] + red[1] + red[2] + red[3];
    s2 = red[4] + red[5] + red[6] + red[7];
    const float mean = s * (1.0f / 1024.0f);
    float var = s2 * (1.0f / 1024.0f) - mean * mean;
    var = fmaxf(var, 0.0f);
    const float rstd = 1.0f / (sqrtf(var) + 1e-6f);
    const int c = tid * 4;
    const float4 g = *(const float4*)(gamma + c);
    const float4 b = *(const float4*)(beta + c);
    bf16x4 o;
    o[0] = (bf16)((v[0] - mean) * rstd * g.x + b.x);
    o[1] = (bf16)((v[1] - mean) * rstd * g.y + b.y);
    o[2] = (bf16)((v[2] - mean) * rstd * g.z + b.z);
    o[3] = (bf16)((v[3] - mean) * rstd * g.w + b.w);
    *(bf16x4*)(out + (size_t)row * 1024 + c) = o;
}

// ---------------------------------------------------------------------------
// gemm_bt: round-0-verified 2-buffer 128x128/BK=32 body, (256,3).
// Used for out-projection only (EPI 1: + fp32 residual -> fp32).
// ---------------------------------------------------------------------------
template <int EPI>
__global__ __launch_bounds__(256, 3) void gemm_bt(const bf16* __restrict__ A,
                                                  const bf16* __restrict__ B,
                                                  int N, int K, int ldk,
                                                  bf16* __restrict__ outb,
                                                  float* __restrict__ outf,
                                                  const float* __restrict__ bias,
                                                  const float* __restrict__ resf) {
    __shared__ alignas(16) bf16 As[2][128 * 32];
    __shared__ alignas(16) bf16 Bs[2][128 * 32];
    const int tid = threadIdx.x;
    const int bm = blockIdx.x, bn = blockIdx.y;
    const int wave = tid >> 6, lane = tid & 63;
    const int wm = (wave >> 1) * 64, wn = (wave & 1) * 64;
    const int l16 = lane & 15, quad = lane >> 4;

    f32x4 acc[4][4] = {};

    const int row0 = tid >> 2, ch0 = tid & 3;
    const int gch = ch0 ^ ((row0 >> 1) & 3);  // source-permuted staging chunk
    const bf16* Ap = A + (size_t)(bm * 128 + row0) * ldk + gch * 8;
    const bf16* Bp = B + (size_t)(bn * 128 + row0) * ldk + gch * 8;
    const size_t rstep = (size_t)64 * ldk;   // row0+64: same swizzle

#pragma unroll
    for (int r = 0; r < 2; r++) {
        load16_lds(Ap + r * rstep, &As[0][tid * 8 + r * 2048]);
        load16_lds(Bp + r * rstep, &Bs[0][tid * 8 + r * 2048]);
    }
    __syncthreads();

    int buf = 0;
    for (int k0 = 0; k0 < K; k0 += 32, buf ^= 1) {
        if (k0 + 32 < K) {
#pragma unroll
            for (int r = 0; r < 2; r++) {
                load16_lds(Ap + r * rstep + k0 + 32, &As[buf ^ 1][tid * 8 + r * 2048]);
                load16_lds(Bp + r * rstep + k0 + 32, &Bs[buf ^ 1][tid * 8 + r * 2048]);
            }
        }
        bf16x8 af[4], bfr[4];
#pragma unroll
        for (int i = 0; i < 4; i++) {
            const int ra = wm + i * 16 + l16;
            af[i] = *(const bf16x8*)(&As[buf][ra * 32 + (quad ^ ((ra >> 1) & 3)) * 8]);
        }
#pragma unroll
        for (int j = 0; j < 4; j++) {
            const int rb = wn + j * 16 + l16;
            bfr[j] = *(const bf16x8*)(&Bs[buf][rb * 32 + (quad ^ ((rb >> 1) & 3)) * 8]);
        }
#pragma unroll
        for (int i = 0; i < 4; i++)
#pragma unroll
            for (int j = 0; j < 4; j++) acc[i][j] = mfma16(af[i], bfr[j], acc[i][j]);
        __syncthreads();
    }

#pragma unroll
    for (int i = 0; i < 4; i++) {
#pragma unroll
        for (int j = 0; j < 4; j++) {
            const int gr0 = bm * 128 + wm + i * 16 + quad * 4;
            const int gc = bn * 128 + wn + j * 16 + l16;
#pragma unroll
            for (int r = 0; r < 4; r++) {
                const float v = acc[i][j][r];
                const size_t idx = (size_t)(gr0 + r) * N + gc;
                if (EPI == 1) {
                    outf[idx] = v + resf[idx];
                } else {
                    outb[idx] = (bf16)v;
                }
            }
        }
    }
}

// ---------------------------------------------------------------------------
// gemm256_8ph: 256x256 GEMM, BK=64, 8 waves (2Mx4N), 4-phase-per-K-tile,
// counted vmcnt(6). Structure correctness-verified in r3 (passed). This
// round's only change: bank swizzle ((row>>1)&3) on BOTH stage & read sides
// (the 0-conflict permutation measured on the 128^2 kernel, same 64 B-row
// geometry). Staging rows step by 128 -> swizzle per-thread invariant, LDS
// dests stay linear for global_load_lds (rule #21).
// Half-tile stage stream per tile T: s0=A.kk0, s2=B.kk0, s1=A.kk1, s3=B.kk1
// issued at (T-2).ph2, (T-2).ph3, (T-2).ph4, (T-1).ph1; end-of-tile
// vmcnt(6) leaves 3 stages in flight, guarantees tile t+1 resident.
// Every stage overwrites a region whose last ds_read retired before the
// previous phase's closing barrier.
// EPI: 2=+bias,GELU -> bf16   4=qkv split store (qk + vt)
//      5=atomicAdd into fp32 (+bias if kz==0), split-K via blockIdx.z
// ---------------------------------------------------------------------------
#define STG_A(bb, rk, tt)                                          \
    do {                                                           \
        const int _ko = ((tt) << 6) + ((rk) << 5);                 \
        load16_lds(Ap + _ko, &As[bb][rk][tid * 8]);                \
        load16_lds(Ap + rstep + _ko, &As[bb][rk][4096 + tid * 8]); \
    } while (0)
#define STG_B(bb, rk, tt)                                          \
    do {                                                           \
        const int _ko = ((tt) << 6) + ((rk) << 5);                 \
        load16_lds(Bp + _ko, &Bs[bb][rk][tid * 8]);                \
        load16_lds(Bp + rstep + _ko, &Bs[bb][rk][4096 + tid * 8]); \
    } while (0)
#define PHASE_OPEN()                       \
    __builtin_amdgcn_s_barrier();          \
    asm volatile("" ::: "memory");         \
    __builtin_amdgcn_s_setprio(1)
#define PHASE_CLOSE()                      \
    __builtin_amdgcn_s_setprio(0);         \
    __builtin_amdgcn_s_barrier();          \
    asm volatile("" ::: "memory")

template <int EPI>
__global__ __launch_bounds__(512, 2) void gemm256_8ph(const bf16* __restrict__ A,
                                                      const bf16* __restrict__ B,
                                                      int N, int K, int ldk,
                                                      bf16* __restrict__ outb,
                                                      float* __restrict__ outf,
                                                      const float* __restrict__ bias,
                                                      bf16* __restrict__ qk,
                                                      bf16* __restrict__ vt) {
    __shared__ alignas(16) bf16 As[2][2][8192];   // [buf][kk][256 rows x 32 cols]
    __shared__ alignas(16) bf16 Bs[2][2][8192];
    const int tid = threadIdx.x;
    const int bm = blockIdx.x, bn = blockIdx.y;
    const int wave = tid >> 6, lane = tid & 63;
    const int wm = (wave >> 2) * 128, wn = (wave & 3) * 64;  // 2x4 wave grid
    const int l16 = lane & 15, quad = lane >> 4;

    f32x4 acc[8][4] = {};

    const size_t koff = (size_t)blockIdx.z * K;
    const int row0 = tid >> 2;                       // 0..127 (sweep row)
    const int gch = (tid & 3) ^ ((row0 >> 1) & 3);   // FIXED swizzle (was row&3)
    const bf16* Ap = A + (size_t)(bm * 256 + row0) * ldk + koff + gch * 8;
    const bf16* Bp = B + (size_t)(bn * 256 + row0) * ldk + koff + gch * 8;
    const size_t rstep = (size_t)128 * ldk;          // rows +128: same swizzle

    const int NT = K >> 6;                           // BK=64 K-tiles (>=2)

    // prologue: 7 half-tile stages (14 loads/wave), then vmcnt(6):
    // tile 0 fully landed, t1.{s0,s2,s1} (3 stages) in flight.
    STG_A(0, 0, 0); STG_B(0, 0, 0); STG_A(0, 1, 0); STG_B(0, 1, 0);
    STG_A(1, 0, 1); STG_B(1, 0, 1); STG_A(1, 1, 1);
    asm volatile("s_waitcnt vmcnt(6)" ::: "memory");
    __builtin_amdgcn_s_barrier();
    asm volatile("" ::: "memory");

    for (int t = 0; t < NT; ++t) {
        const int buf = t & 1;
        bf16x8 af[8], bj0, bj1;

        // ---- phase 1: kk0, j=0,1 ----
#pragma unroll
        for (int i = 0; i < 8; i++) {
            const int ra = wm + i * 16 + l16;
            af[i] = *(const bf16x8*)&As[buf][0][ra * 32 + (quad ^ ((ra >> 1) & 3)) * 8];
        }
        {
            const int rb0 = wn + l16, rb1 = wn + 16 + l16;
            bj0 = *(const bf16x8*)&Bs[buf][0][rb0 * 32 + (quad ^ ((rb0 >> 1) & 3)) * 8];
            bj1 = *(const bf16x8*)&Bs[buf][0][rb1 * 32 + (quad ^ ((rb1 >> 1) & 3)) * 8];
        }
        if (t + 1 < NT) STG_B(buf ^ 1, 1, t + 1);   // (t+1).s3
        PHASE_OPEN();
#pragma unroll
        for (int i = 0; i < 8; i++) {
            acc[i][0] = mfma16(af[i], bj0, acc[i][0]);
            acc[i][1] = mfma16(af[i], bj1, acc[i][1]);
        }
        PHASE_CLOSE();

        // ---- phase 2: kk0, j=2,3 (A reused in regs) ----
        {
            const int rb2 = wn + 32 + l16, rb3 = wn + 48 + l16;
            bj0 = *(const bf16x8*)&Bs[buf][0][rb2 * 32 + (quad ^ ((rb2 >> 1) & 3)) * 8];
            bj1 = *(const bf16x8*)&Bs[buf][0][rb3 * 32 + (quad ^ ((rb3 >> 1) & 3)) * 8];
        }
        if (t + 2 < NT) STG_A(buf, 0, t + 2);       // (t+2).s0, region read in ph1
        PHASE_OPEN();
#pragma unroll
        for (int i = 0; i < 8; i++) {
            acc[i][2] = mfma16(af[i], bj0, acc[i][2]);
            acc[i][3] = mfma16(af[i], bj1, acc[i][3]);
        }
        PHASE_CLOSE();

        // ---- phase 3: kk1, j=0,1 ----
#pragma unroll
        for (int i = 0; i < 8; i++) {
            const int ra = wm + i * 16 + l16;
            af[i] = *(const bf16x8*)&As[buf][1][ra * 32 + (quad ^ ((ra >> 1) & 3)) * 8];
        }
        {
            const int rb0 = wn + l16, rb1 = wn + 16 + l16;
            bj0 = *(const bf16x8*)&Bs[buf][1][rb0 * 32 + (quad ^ ((rb0 >> 1) & 3)) * 8];
            bj1 = *(const bf16x8*)&Bs[buf][1][rb1 * 32 + (quad ^ ((rb1 >> 1) & 3)) * 8];
        }
        if (t + 2 < NT) STG_B(buf, 0, t + 2);       // (t+2).s2, region read ph1/ph2
        PHASE_OPEN();
#pragma unroll
        for (int i = 0; i < 8; i++) {
            acc[i][0] = mfma16(af[i], bj0, acc[i][0]);
            acc[i][1] = mfma16(af[i], bj1, acc[i][1]);
        }
        PHASE_CLOSE();

        // ---- phase 4: kk1, j=2,3 ----
        {
            const int rb2 = wn + 32 + l16, rb3 = wn + 48 + l16;
            bj0 = *(const bf16x8*)&Bs[buf][1][rb2 * 32 + (quad ^ ((rb2 >> 1) & 3)) * 8];
            bj1 = *(const bf16x8*)&Bs[buf][1][rb3 * 32 + (quad ^ ((rb3 >> 1) & 3)) * 8];
        }
        if (t + 2 < NT) STG_A(buf, 1, t + 2);       // (t+2).s1, region read ph3
        __builtin_amdgcn_s_barrier();
        asm volatile("" ::: "memory");
        __builtin_amdgcn_s_setprio(1);
#pragma unroll
        for (int i = 0; i < 8; i++) {
            acc[i][2] = mfma16(af[i], bj0, acc[i][2]);
            acc[i][3] = mfma16(af[i], bj1, acc[i][3]);
        }
        __builtin_amdgcn_s_setprio(0);
        // end-of-tile counted wait: tile t+1 resident; 3 stages stay in flight.
        if (t + 2 < NT) {
            asm volatile("s_waitcnt vmcnt(6)" ::: "memory");
        } else if (t + 1 < NT) {
            asm volatile("s_waitcnt vmcnt(0)" ::: "memory");
        }
        if (t + 1 < NT) {
            __builtin_amdgcn_s_barrier();
            asm volatile("" ::: "memory");
        }
    }

#pragma unroll
    for (int i = 0; i < 8; i++) {
#pragma unroll
        for (int j = 0; j < 4; j++) {
            const int gr0 = bm * 256 + wm + i * 16 + quad * 4;
            const int gc = bn * 256 + wn + j * 16 + l16;
            float bv = 0.0f;
            if (EPI == 2) bv = bias[gc];
            if (EPI == 5 && bias && blockIdx.z == 0) bv = bias[gc];
            if (EPI == 4 && gc >= 2048) {
                // V part -> vt[b][h][d][s], packed over 4 consecutive s
                const int n = gc - 2048;
                const int hh = n >> 6, dd = n & 63;
                const int bb = gr0 >> 11, ss = gr0 & 2047;
                bf16x4 pk;
#pragma unroll
                for (int r = 0; r < 4; r++) pk[r] = (bf16)acc[i][j][r];
                *(bf16x4*)(vt + ((size_t)((bb * 16 + hh) * 64 + dd)) * 2048 + ss) = pk;
            } else {
#pragma unroll
                for (int r = 0; r < 4; r++) {
                    const float v = acc[i][j][r];
                    const size_t idx = (size_t)(gr0 + r) * N + gc;
                    if (EPI == 2) {
                        const float t = v + bv;
                        outb[idx] = (bf16)(0.5f * t * (1.0f + erff(t * 0.70710678118654752f)));
                    } else if (EPI == 5) {
                        atomicAdd(&outf[idx], v + bv);
                    } else {  // EPI 4, Q/K part: row-stride 2048
                        qk[(size_t)(gr0 + r) * 2048 + gc] = (bf16)v;
                    }
                }
            }
        }
    }
}
#undef STG_A
#undef STG_B
#undef PHASE_OPEN
#undef PHASE_CLOSE

// ---------------------------------------------------------------------------
// Causal flash attention v3 (r5 version, verified). Fixed-shift softmax.
// ---------------------------------------------------------------------------
__global__ __launch_bounds__(256, 4) void flash_attn(const bf16* __restrict__ qk,
                                                     const bf16* __restrict__ vt,
                                                     bf16* __restrict__ attn) {
    __shared__ alignas(16) bf16 Ks[64 * 72];
    __shared__ alignas(16) bf16 Vs[64 * 72];
    __shared__ alignas(16) bf16 Ps[4][16 * 72];
    const int tid = threadIdx.x;
    const int wave = tid >> 6, lane = tid & 63;
    const int l16 = lane & 15, quad = lane >> 4;
    const int bh = blockIdx.x;
    const int qt = 31 - blockIdx.y;
    const int b = bh >> 4, h = bh & 15;
    const int q0w = qt * 64 + wave * 16;
    const bf16* qkb = qk + (size_t)b * 2048 * 2048;
    const bf16* vtb = vt + (size_t)bh * 64 * 2048;

    bf16x8 qf[2];
#pragma unroll
    for (int c = 0; c < 2; c++) {
        bf16x8 v = *(const bf16x8*)(qkb + (size_t)(q0w + l16) * 2048 +
                                    h * 64 + c * 32 + quad * 8);
#pragma unroll
        for (int e = 0; e < 8; e++) v[e] = (bf16)((float)v[e] * 0.125f);
        qf[c] = v;
    }

    float lsum[4] = {0.0f, 0.0f, 0.0f, 0.0f};
    f32x4 o[4] = {};

    const int ntiles = qt + 1;
    for (int t = 0; t < ntiles; t++) {
        const int k0 = t * 64;
#pragma unroll
        for (int i = 0; i < 2; i++) {
            const int r = i * 32 + (tid >> 3), ch = tid & 7;
            *(uint4*)(&Ks[r * 72 + ch * 8]) =
                *(const uint4*)(qkb + (size_t)(k0 + r) * 2048 + 1024 + h * 64 + ch * 8);
            *(uint4*)(&Vs[r * 72 + ch * 8]) =
                *(const uint4*)(vtb + (size_t)r * 2048 + k0 + ch * 8);
        }
        __syncthreads();
        f32x4 s[4];
        __builtin_amdgcn_s_setprio(1);
#pragma unroll
        for (int kt = 0; kt < 4; kt++) {
            const bf16x8 k0f = *(const bf16x8*)(&Ks[(kt * 16 + l16) * 72 + quad * 8]);
            const bf16x8 k1f = *(const bf16x8*)(&Ks[(kt * 16 + l16) * 72 + 32 + quad * 8]);
            s[kt] = mfma16(qf[1], k1f, mfma16(qf[0], k0f, (f32x4){0, 0, 0, 0}));
        }
        __builtin_amdgcn_s_setprio(0);
        const bool need_mask = (t == ntiles - 1);
#pragma unroll
        for (int r = 0; r < 4; r++) {
            const int qrow = q0w + quad * 4 + r;
            float e0 = exp2f(fmaf(s[0][r], LOG2E, NSHIFT));
            float e1 = exp2f(fmaf(s[1][r], LOG2E, NSHIFT));
            float e2 = exp2f(fmaf(s[2][r], LOG2E, NSHIFT));
            float e3 = exp2f(fmaf(s[3][r], LOG2E, NSHIFT));
            if (need_mask) {
                if (k0 + l16 > qrow) e0 = 0.0f;
                if (k0 + 16 + l16 > qrow) e1 = 0.0f;
                if (k0 + 32 + l16 > qrow) e2 = 0.0f;
                if (k0 + 48 + l16 > qrow) e3 = 0.0f;
            }
            lsum[r] += (e0 + e1) + (e2 + e3);
            bf16* pp = &Ps[wave][(quad * 4 + r) * 72];
            pp[l16] = (bf16)e0;
            pp[16 + l16] = (bf16)e1;
            pp[32 + l16] = (bf16)e2;
            pp[48 + l16] = (bf16)e3;
        }
        __builtin_amdgcn_s_setprio(1);
#pragma unroll
        for (int c = 0; c < 2; c++) {
            const bf16x8 pf = *(const bf16x8*)(&Ps[wave][l16 * 72 + c * 32 + quad * 8]);
#pragma unroll
            for (int dt = 0; dt < 4; dt++) {
                const bf16x8 vf =
                    *(const bf16x8*)(&Vs[(dt * 16 + l16) * 72 + c * 32 + quad * 8]);
                o[dt] = mfma16(pf, vf, o[dt]);
            }
        }
        __builtin_amdgcn_s_setprio(0);
        __syncthreads();
    }

#pragma unroll
    for (int r = 0; r < 4; r++) {
#pragma unroll
        for (int off = 1; off < 16; off <<= 1) lsum[r] += __shfl_xor(lsum[r], off);
        lsum[r] = 1.0f / fmaxf(lsum[r], 1e-30f);
    }
    bf16* ob = attn + (size_t)b * 2048 * 1024;
#pragma unroll
    for (int dt = 0; dt < 4; dt++)
#pragma unroll
        for (int r = 0; r < 4; r++) {
            const int q = q0w + quad * 4 + r;
            ob[(size_t)q * 1024 + h * 64 + dt * 16 + l16] = (bf16)(o[dt][r] * lsum[r]);
        }
}

// ---------------------------------------------------------------------------
extern "C" void kernel_launch(void* const* d_in, const int* in_sizes, int n_in,
                              void* d_out, int out_size, void* d_ws, size_t ws_size,
                              hipStream_t stream) {
    const float* x    = (const float*)d_in[0];
    const float* Wqkv = (const float*)d_in[2];
    const float* Wout = (const float*)d_in[3];
    const float* W1   = (const float*)d_in[4];
    const float* b1   = (const float*)d_in[5];
    const float* W2   = (const float*)d_in[6];
    const float* b2   = (const float*)d_in[7];
    const float* g1   = (const float*)d_in[8];
    const float* be1  = (const float*)d_in[9];
    const float* g2   = (const float*)d_in[10];
    const float* be2  = (const float*)d_in[11];

    char* ws = (char*)d_ws;
    bf16* Wb     = (bf16*)(ws);                 // all 4 weights, contiguous 24 MiB
    bf16* Wqkv_b = (bf16*)(ws);
    bf16* Wout_b = (bf16*)(ws + (6u << 20));
    bf16* W1_b   = (bf16*)(ws + (8u << 20));
    bf16* W2_b   = (bf16*)(ws + (16u << 20));
    bf16* h      = (bf16*)(ws + (24u << 20));
    bf16* qkbuf  = (bf16*)(ws + (32u << 20));
    bf16* vtbuf  = (bf16*)(ws + (48u << 20));
    bf16* attn   = (bf16*)(ws + (56u << 20));
    bf16* act    = (bf16*)(ws + (32u << 20));   // aliases qk/vt/attn post-attention
    float* x2    = (float*)d_out;               // residual stream lives in d_out

    // 0) all weights fp32 -> bf16 (one launch)
    cvt4_kernel<<<12288, 256, 0, stream>>>(Wqkv, Wout, W1, W2, Wb);

    // 1) h = LN1(x)
    ln_kernel<<<4096, 256, 0, stream>>>(x, h, g1, be1);
    // 2) qkv = h @ Wqkv^T -> qk rows + V^T   (8-phase 256^2, 16x12 grid)
    gemm256_8ph<4><<<dim3(16, 12), 512, 0, stream>>>(h, Wqkv_b, 3072, 1024, 1024,
                                                     nullptr, nullptr, nullptr,
                                                     qkbuf, vtbuf);
    // 3) attn = causal_flash(qk, vt)
    flash_attn<<<dim3(32, 32), 256, 0, stream>>>(qkbuf, vtbuf, attn);
    // 4) x2 = attn @ Wout^T + x   (fp32, into d_out; 2-buf r0 body)
    gemm_bt<1><<<dim3(32, 8), 256, 0, stream>>>(attn, Wout_b, 1024, 1024, 1024,
                                                nullptr, x2, nullptr, x);
    // 5) h = LN2(x2)
    ln_kernel<<<4096, 256, 0, stream>>>(x2, h, g2, be2);
    // 6) act = gelu(h @ W1^T + b1)   (8-phase 256^2, 16x16 = 256 blocks)
    gemm256_8ph<2><<<dim3(16, 16), 512, 0, stream>>>(h, W1_b, 4096, 1024, 1024,
                                                     act, nullptr, b1, nullptr, nullptr);
    // 7) out += act @ W2^T + b2   (8-phase, split-K=4 -> 256 blocks, atomicAdd)
    gemm256_8ph<5><<<dim3(16, 4, 4), 512, 0, stream>>>(act, W2_b, 1024, 1024, 4096,
                                                       nullptr, x2, b2, nullptr, nullptr);
}